// Round 2
// baseline (326.369 us; speedup 1.0000x reference)
//
#include <hip/hip_runtime.h>
#include <hip/hip_bf16.h>

typedef unsigned short u16;
typedef short bf16x8_t __attribute__((ext_vector_type(8)));
typedef float f32x4_t  __attribute__((ext_vector_type(4)));

__device__ __forceinline__ u16 f2bf(float f) {
    __hip_bfloat16 h = __float2bfloat16(f);
    union { __hip_bfloat16 b; u16 u; } cv; cv.b = h; return cv.u;
}

// async global->LDS, 16B per lane; lds dest = wave-uniform base + lane*16
__device__ __forceinline__ void g2l16(const void* g, void* l) {
    __builtin_amdgcn_global_load_lds(
        (const __attribute__((address_space(1))) unsigned int*)g,
        (__attribute__((address_space(3))) unsigned int*)l, 16, 0, 0);
}

// ---------------- vectorized cast fp32 -> bf16 (4 elems/thread) ----------------
__global__ __launch_bounds__(256) void k_cast_bf16v(const float* __restrict__ in,
                                                    u16* __restrict__ out, int n4) {
    int i = blockIdx.x * 256 + threadIdx.x;
    if (i < n4) {
        float4 f = ((const float4*)in)[i];
        ushort4 o;
        o.x = f2bf(f.x); o.y = f2bf(f.y); o.z = f2bf(f.z); o.w = f2bf(f.w);
        ((ushort4*)out)[i] = o;
    }
}

// ---------------- fused transpose+cast for Wo/W1/W2 (one launch) ----------------
__global__ __launch_bounds__(256)
void k_transpose3(const float* __restrict__ Wo, const float* __restrict__ W1,
                  const float* __restrict__ W2, u16* __restrict__ Wot,
                  u16* __restrict__ W1t, u16* __restrict__ W2t) {
    int id = blockIdx.x;
    const float* in; u16* out; int R, C, tx, ty;
    if (id < 256)       { in = Wo; out = Wot; R = 1024; C = 1024; tx = id & 15; ty = id >> 4; }
    else if (id < 1280) { id -= 256; in = W1; out = W1t; R = 1024; C = 4096; tx = id & 63; ty = id >> 6; }
    else                { id -= 1280; in = W2; out = W2t; R = 4096; C = 1024; tx = id & 15; ty = id >> 4; }
    __shared__ float t[64][65];
    int r0 = ty * 64, c0 = tx * 64;
    int lc = threadIdx.x & 63, lr = threadIdx.x >> 6;
#pragma unroll
    for (int p = 0; p < 16; ++p) {
        int rr = p * 4 + lr;
        t[rr][lc] = in[(size_t)(r0 + rr) * C + c0 + lc];
    }
    __syncthreads();
#pragma unroll
    for (int p = 0; p < 16; ++p) {
        int cc = p * 4 + lr;
        out[(size_t)(c0 + cc) * R + r0 + lc] = f2bf(t[lc][cc]);
    }
}

// ---------------- Wq/Wk/Wv [H,D,DK] -> fused Bt [3072][1024] bf16 ----------------
__global__ __launch_bounds__(256)
void k_qkvw_t(const float* __restrict__ Wq, const float* __restrict__ Wk,
              const float* __restrict__ Wv, u16* __restrict__ out) {
    const float* in = blockIdx.z == 0 ? Wq : (blockIdx.z == 1 ? Wk : Wv);
    in += (size_t)blockIdx.y * 65536;                       // head slab [1024][64]
    u16* o = out + ((size_t)blockIdx.z * 1024 + blockIdx.y * 64) * 1024;
    __shared__ float t[64][65];
    int d0 = blockIdx.x * 64;
    int lc = threadIdx.x & 63, lr = threadIdx.x >> 6;
#pragma unroll
    for (int p = 0; p < 16; ++p) {
        int rr = p * 4 + lr;
        t[rr][lc] = in[(size_t)(d0 + rr) * 64 + lc];
    }
    __syncthreads();
#pragma unroll
    for (int p = 0; p < 16; ++p) {
        int cc = p * 4 + lr;
        o[(size_t)cc * 1024 + d0 + lc] = f2bf(t[lc][cc]);
    }
}

// ---------------- V [bh][s][dk] -> VT [bh][dk][s] bf16 (padded-LDS transpose) ----------------
__global__ __launch_bounds__(256)
void k_vt(const u16* __restrict__ V, u16* __restrict__ VT) {
    __shared__ u16 t[64 * 72];
    int bh = blockIdx.y, s0 = blockIdx.x * 64;
    const u16* Vp = V + (size_t)bh * 65536;
    u16* Tp = VT + (size_t)bh * 65536;
    int tid = threadIdx.x;
    int r = tid >> 3, c = (tid & 7) * 8;
    *(uint4*)&t[r * 72 + c]        = *(const uint4*)&Vp[(size_t)(s0 + r) * 64 + c];
    *(uint4*)&t[(r + 32) * 72 + c] = *(const uint4*)&Vp[(size_t)(s0 + r + 32) * 64 + c];
    __syncthreads();
    int d = tid >> 2, sl0 = (tid & 3) * 16;
    uint4 outv[2];
    u16* ov = (u16*)outv;
#pragma unroll
    for (int j = 0; j < 16; ++j) ov[j] = t[(sl0 + j) * 72 + d];
    *(uint4*)&Tp[(size_t)d * 1024 + s0 + sl0]     = outv[0];
    *(uint4*)&Tp[(size_t)d * 1024 + s0 + sl0 + 8] = outv[1];
}

// ---------------- 128x128 bf16 GEMM, B pre-transposed, BK=64 (split-K kernel) ----------------
// EPI 0: fp32 partial store at out + z*M*N (split-K). Kept for O-proj (N too narrow for 256 tiles).
template<int EPI>
__global__ __launch_bounds__(256, 4)
void k_gemm_bt(const u16* __restrict__ A, const u16* __restrict__ Bt,
               const float* __restrict__ bias0, void* __restrict__ out,
               int M, int N, int K, int kchunk)
{
    __shared__ __align__(16) u16 As[2 * 128 * 32];
    __shared__ __align__(16) u16 Bs[2 * 128 * 32];
    int tid = threadIdx.x;
    int wave = tid >> 6, lane = tid & 63;

    int nx = gridDim.x, nwg = nx * gridDim.y;
    int f  = blockIdx.x + nx * blockIdx.y;
    int f2 = (f & 7) * (nwg >> 3) + (f >> 3);
    int bx = f2 % nx, by = f2 / nx;
    int row0 = by * 128, col0 = bx * 128;

    int z = blockIdx.z;
    int kbeg = z * kchunk;

    int lrow = lane >> 2, lcol = (lane & 3) * 8;
    const u16* pA0 = A  + (size_t)(row0 + wave * 16 + lrow) * K + kbeg + lcol;
    const u16* pA1 = pA0 + (size_t)64 * K;
    const u16* pB0 = Bt + (size_t)(col0 + wave * 16 + lrow) * K + kbeg + lcol;
    const u16* pB1 = pB0 + (size_t)64 * K;
    u16* lA0 = &As[wave * 512];
    u16* lA1 = &As[2048 + wave * 512];
    u16* lB0 = &Bs[wave * 512];
    u16* lB1 = &Bs[2048 + wave * 512];

    int wm = (wave >> 1) * 64, wn = (wave & 1) * 64;
    int quad = lane >> 4, l16 = lane & 15;

    f32x4_t acc[4][4];
#pragma unroll
    for (int i = 0; i < 4; i++)
#pragma unroll
        for (int j = 0; j < 4; j++) acc[i][j] = f32x4_t{0.f, 0.f, 0.f, 0.f};

    for (int kk = 0; kk < kchunk; kk += 64) {
        __syncthreads();
        g2l16(pA0, lA0);      g2l16(pA1, lA1);
        g2l16(pA0 + 32, lA0 + 4096); g2l16(pA1 + 32, lA1 + 4096);
        g2l16(pB0, lB0);      g2l16(pB1, lB1);
        g2l16(pB0 + 32, lB0 + 4096); g2l16(pB1 + 32, lB1 + 4096);
        pA0 += 64; pA1 += 64; pB0 += 64; pB1 += 64;
        __syncthreads();

#pragma unroll
        for (int s = 0; s < 2; ++s) {
            const u16* as = &As[s * 4096];
            const u16* bs = &Bs[s * 4096];
            bf16x8_t a[4], b[4];
#pragma unroll
            for (int i = 0; i < 4; ++i)
                a[i] = *(const bf16x8_t*)&as[(wm + i * 16 + l16) * 32 + quad * 8];
#pragma unroll
            for (int j = 0; j < 4; ++j)
                b[j] = *(const bf16x8_t*)&bs[(wn + j * 16 + l16) * 32 + quad * 8];
#pragma unroll
            for (int i = 0; i < 4; ++i)
#pragma unroll
                for (int j = 0; j < 4; ++j)
                    acc[i][j] = __builtin_amdgcn_mfma_f32_16x16x32_bf16(a[i], b[j], acc[i][j], 0, 0, 0);
        }
    }

#pragma unroll
    for (int i = 0; i < 4; ++i)
#pragma unroll
        for (int j = 0; j < 4; ++j)
#pragma unroll
            for (int r = 0; r < 4; ++r) {
                int row = row0 + wm + i * 16 + quad * 4 + r;
                int col = col0 + wn + j * 16 + l16;
                ((float*)out)[(size_t)z * M * N + (size_t)row * N + col] = acc[i][j][r];
            }
}

// ================= 256x256 8-phase bf16 GEMM (T3+T4+T2+T5), BK=64 =================
// 8 waves = 2M x 4N, per-wave 128x64 output (acc[8][4]).
// LDS 128 KiB: A/B each [2 bufs][256][64] u16, XOR-swizzled (16B chunk ^= row&7)
// on both the stage SOURCE address and the ds_read address (involution, m201/G21).
// Per K-tile t (4 phases):
//   P1: ds_read A(m0)+B(n0); stage (t+1).A0 -> buf^1 ; MFMA quad (m0,n0)
//   P2: ds_read B(n1)      ; stage (t+1).A1 -> buf^1 ; MFMA quad (m0,n1)
//   P3: ds_read A(m1)      ; stage (t+2).B0 -> buf   ; MFMA quad (m1,n0)
//   P4:                      stage (t+2).B1 -> buf   ; MFMA quad (m1,n1); vmcnt(4)
// Region retirement: B of buf retired after P2 barrier, A after P3 barrier ->
// every stage targets a retired region (barrier-ordered). vmcnt(4) at P4 ensures
// tile t+1 (last half staged at P2) landed; 2 half-tiles stay in flight (never 0).
// EPI 0: split-K fp32 partial; EPI 1: relu+bias bf16; EPI 2: QKV scatter.
template<int EPI>
__global__ __launch_bounds__(512, 2)
void k_gemm8(const u16* __restrict__ A, const u16* __restrict__ Bt,
             const float* __restrict__ bias0, const float* __restrict__ bias1,
             const float* __restrict__ bias2, void* __restrict__ out,
             int M, int N, int K, int kchunk)
{
    __shared__ __align__(16) u16 As[2][16384];
    __shared__ __align__(16) u16 Bs[2][16384];

    const int tid = threadIdx.x;
    const int wave = tid >> 6, lane = tid & 63;
    const int quad = lane >> 4, l16 = lane & 15;
    const int wm = (wave >> 2) * 128;       // 2 M-warps: rows 0-127 / 128-255
    const int wn = (wave & 3) * 64;         // 4 N-warps: cols 0/64/128/192

    // XCD-chunked bijective swizzle within each z-slice (nwg % 8 == 0 for all uses)
    int nx = gridDim.x, nwg = nx * gridDim.y;
    int f  = blockIdx.x + nx * blockIdx.y;
    int f2 = (f & 7) * (nwg >> 3) + (f >> 3);
    int row0 = (f2 / nx) * 256, col0 = (f2 % nx) * 256;
    int z = blockIdx.z, kbeg = z * kchunk;
    int nk = kchunk >> 6;

    // staging source: thread -> (row rr0 / rr0+64, 16B chunk cg), source col XOR'd
    const int rr0 = tid >> 3, cg = tid & 7;
    const int xc = (cg ^ (rr0 & 7)) * 8;              // u16 col within 64-wide K-slab
    const u16* Ag = A  + (size_t)(row0 + rr0) * K + kbeg + xc;
    const u16* Bg = Bt + (size_t)(col0 + rr0) * K + kbeg + xc;
    const int ldst = tid * 8;                          // u16 LDS offset, round j=0

#define STA(bsel, h, kt) do { \
    const u16* _s = Ag + (size_t)(h) * 128 * K + (size_t)(kt) * 64; \
    g2l16(_s, &As[bsel][(h) * 8192 + ldst]); \
    g2l16(_s + (size_t)64 * K, &As[bsel][(h) * 8192 + 4096 + ldst]); } while (0)
#define STB(bsel, h, kt) do { \
    const u16* _s = Bg + (size_t)(h) * 128 * K + (size_t)(kt) * 64; \
    g2l16(_s, &Bs[bsel][(h) * 8192 + ldst]); \
    g2l16(_s + (size_t)64 * K, &Bs[bsel][(h) * 8192 + 4096 + ldst]); } while (0)

    // swizzled fragment reads (row*64 u16, chunk = (ks*4+quad) ^ (row&7))
#define RDA(b, mi, ks) (*(const bf16x8_t*)&As[b][(wm + (mi) * 16 + l16) * 64 + ((((ks) * 4 + quad) ^ (l16 & 7)) * 8)])
#define RDB(b, nj, ks) (*(const bf16x8_t*)&Bs[b][(wn + (nj) * 16 + l16) * 64 + ((((ks) * 4 + quad) ^ (l16 & 7)) * 8)])

    f32x4_t acc[8][4];
#pragma unroll
    for (int i = 0; i < 8; ++i)
#pragma unroll
        for (int j = 0; j < 4; ++j) acc[i][j] = f32x4_t{0.f, 0.f, 0.f, 0.f};

    // prologue: t0 fully, t1.B0/B1; wait t0 landed (keep t1 halves in flight)
    STA(0, 0, 0); STA(0, 1, 0); STB(0, 0, 0); STB(0, 1, 0);
    if (nk > 1) {
        STB(1, 0, 1); STB(1, 1, 1);
        asm volatile("s_waitcnt vmcnt(4)" ::: "memory");
    } else {
        asm volatile("s_waitcnt vmcnt(0)" ::: "memory");
    }
    __builtin_amdgcn_s_barrier();

    bf16x8_t av[4][2], bv0[2][2], bv1[2][2];
    for (int t = 0; t < nk; ++t) {
        int b = t & 1, bn = b ^ 1;
        // ---- P1: A(m0) + B(n0) reads; stage (t+1).A0
#pragma unroll
        for (int i = 0; i < 4; ++i) { av[i][0] = RDA(b, i, 0); av[i][1] = RDA(b, i, 1); }
#pragma unroll
        for (int j = 0; j < 2; ++j) { bv0[j][0] = RDB(b, j, 0); bv0[j][1] = RDB(b, j, 1); }
        if (t + 1 < nk) STA(bn, 0, t + 1);
        __builtin_amdgcn_s_barrier();
        __builtin_amdgcn_s_setprio(1);
#pragma unroll
        for (int i = 0; i < 4; ++i)
#pragma unroll
            for (int j = 0; j < 2; ++j) {
                acc[i][j] = __builtin_amdgcn_mfma_f32_16x16x32_bf16(av[i][0], bv0[j][0], acc[i][j], 0, 0, 0);
                acc[i][j] = __builtin_amdgcn_mfma_f32_16x16x32_bf16(av[i][1], bv0[j][1], acc[i][j], 0, 0, 0);
            }
        __builtin_amdgcn_s_setprio(0);
        __builtin_amdgcn_s_barrier();
        // ---- P2: B(n1) reads; stage (t+1).A1
#pragma unroll
        for (int j = 0; j < 2; ++j) { bv1[j][0] = RDB(b, 2 + j, 0); bv1[j][1] = RDB(b, 2 + j, 1); }
        if (t + 1 < nk) STA(bn, 1, t + 1);
        __builtin_amdgcn_s_barrier();
        __builtin_amdgcn_s_setprio(1);
#pragma unroll
        for (int i = 0; i < 4; ++i)
#pragma unroll
            for (int j = 0; j < 2; ++j) {
                acc[i][2 + j] = __builtin_amdgcn_mfma_f32_16x16x32_bf16(av[i][0], bv1[j][0], acc[i][2 + j], 0, 0, 0);
                acc[i][2 + j] = __builtin_amdgcn_mfma_f32_16x16x32_bf16(av[i][1], bv1[j][1], acc[i][2 + j], 0, 0, 0);
            }
        __builtin_amdgcn_s_setprio(0);
        __builtin_amdgcn_s_barrier();
        // ---- P3: A(m1) reads (A region of b retires here); stage (t+2).B0 -> b
#pragma unroll
        for (int i = 0; i < 4; ++i) { av[i][0] = RDA(b, 4 + i, 0); av[i][1] = RDA(b, 4 + i, 1); }
        if (t + 2 < nk) STB(b, 0, t + 2);
        __builtin_amdgcn_s_barrier();
        __builtin_amdgcn_s_setprio(1);
#pragma unroll
        for (int i = 0; i < 4; ++i)
#pragma unroll
            for (int j = 0; j < 2; ++j) {
                acc[4 + i][j] = __builtin_amdgcn_mfma_f32_16x16x32_bf16(av[i][0], bv0[j][0], acc[4 + i][j], 0, 0, 0);
                acc[4 + i][j] = __builtin_amdgcn_mfma_f32_16x16x32_bf16(av[i][1], bv0[j][1], acc[4 + i][j], 0, 0, 0);
            }
        __builtin_amdgcn_s_setprio(0);
        __builtin_amdgcn_s_barrier();
        // ---- P4: stage (t+2).B1 -> b; counted vmcnt (never 0 mid-loop)
        if (t + 2 < nk) STB(b, 1, t + 2);
        __builtin_amdgcn_s_barrier();
        __builtin_amdgcn_s_setprio(1);
#pragma unroll
        for (int i = 0; i < 4; ++i)
#pragma unroll
            for (int j = 0; j < 2; ++j) {
                acc[4 + i][2 + j] = __builtin_amdgcn_mfma_f32_16x16x32_bf16(av[i][0], bv1[j][0], acc[4 + i][2 + j], 0, 0, 0);
                acc[4 + i][2 + j] = __builtin_amdgcn_mfma_f32_16x16x32_bf16(av[i][1], bv1[j][1], acc[4 + i][2 + j], 0, 0, 0);
            }
        __builtin_amdgcn_s_setprio(0);
        if (t + 1 < nk) {
            if (t + 2 < nk) asm volatile("s_waitcnt vmcnt(4)" ::: "memory");
            else            asm volatile("s_waitcnt vmcnt(0)" ::: "memory");
        }
        __builtin_amdgcn_s_barrier();
    }
#undef STA
#undef STB
#undef RDA
#undef RDB

#pragma unroll
    for (int mi = 0; mi < 8; ++mi)
#pragma unroll
        for (int nj = 0; nj < 4; ++nj)
#pragma unroll
            for (int r = 0; r < 4; ++r) {
                int row = row0 + wm + mi * 16 + quad * 4 + r;
                int col = col0 + wn + nj * 16 + l16;
                float v = acc[mi][nj][r];
                if (EPI == 0) {
                    ((float*)out)[(size_t)z * M * N + (size_t)row * N + col] = v;
                } else if (EPI == 1) {
                    ((u16*)out)[(size_t)row * N + col] = f2bf(fmaxf(v + bias0[col], 0.f));
                } else {
                    int proj = col >> 10, within = col & 1023;
                    const float* bp = proj == 0 ? bias0 : (proj == 1 ? bias1 : bias2);
                    v += bp[within];
                    if (proj == 0) v *= 0.18033688f;   // 0.125 * log2(e)
                    int h = within >> 6, kq = within & 63;
                    int b_ = row >> 10, s_ = row & 1023;
                    size_t bh = (size_t)((b_ << 4) + h);
                    ((u16*)out)[(size_t)proj * 4194304 + bh * 65536 + (s_ << 6) + kq] = f2bf(v);
                }
            }
}

// ---------------- flash attention v3 (no-max softmax, MFMA row-sum) ----------------
// XCD swizzle: all 8 q-blocks of one bh land on the same XCD -> K/V (256KB/bh) L2-resident.
__global__ __launch_bounds__(512, 4)
void k_attn(const u16* __restrict__ Qg, const u16* __restrict__ Kg,
            const u16* __restrict__ VTg, u16* __restrict__ Og)
{
    __shared__ __align__(16) u16 Ks[64 * 64];
    __shared__ __align__(16) u16 Vs[64 * 64];
    __shared__ __align__(16) u16 Ps[128 * 64];

    int tid = threadIdx.x, wave = tid >> 6, lane = tid & 63;
    int quad = lane >> 4, l16 = lane & 15;

    int f  = blockIdx.x + gridDim.x * blockIdx.y;
    int f2 = (f & 7) * ((gridDim.x * gridDim.y) >> 3) + (f >> 3);
    int bh = f2 >> 3;
    int q0 = (f2 & 7) * 128;
    int wrow = wave * 16;

    const u16* Qp  = Qg  + (size_t)bh * 65536;
    const u16* Kp  = Kg  + (size_t)bh * 65536;
    const u16* VTp = VTg + (size_t)bh * 65536;

    int arow_g = q0 + wrow + l16;
    bf16x8_t aq0 = *(const bf16x8_t*)&Qp[(size_t)arow_g * 64 + quad * 8];
    bf16x8_t aq1 = *(const bf16x8_t*)&Qp[(size_t)arow_g * 64 + 32 + quad * 8];

    int srow = tid >> 3, scb = tid & 7;
    uint4 kreg = *(const uint4*)&Kp[(size_t)srow * 64 + scb * 8];
    uint4 vreg = *(const uint4*)&VTp[(size_t)srow * 1024 + scb * 8];
    u16* kdst = &Ks[srow * 64 + ((scb ^ (srow & 7)) * 8)];
    u16* vdst = &Vs[srow * 64 + ((scb ^ (srow & 7)) * 8)];

    f32x4_t o[4], lsum;
#pragma unroll
    for (int nt = 0; nt < 4; ++nt) o[nt] = f32x4_t{0.f, 0.f, 0.f, 0.f};
    lsum = f32x4_t{0.f, 0.f, 0.f, 0.f};

    bf16x8_t ones;
#pragma unroll
    for (int j = 0; j < 8; ++j) ones[j] = (short)0x3F80;

    int a7 = l16 & 7;

    for (int kv0 = 0; kv0 < 1024; kv0 += 64) {
        __syncthreads();
        *(uint4*)kdst = kreg;
        *(uint4*)vdst = vreg;
        __syncthreads();
        if (kv0 < 960) {
            kreg = *(const uint4*)&Kp[(size_t)(kv0 + 64 + srow) * 64 + scb * 8];
            vreg = *(const uint4*)&VTp[(size_t)srow * 1024 + kv0 + 64 + scb * 8];
        }

        f32x4_t s[4];
#pragma unroll
        for (int nt = 0; nt < 4; ++nt) {
            int brow = nt * 16 + l16;
            bf16x8_t bk0 = *(const bf16x8_t*)&Ks[brow * 64 + ((quad ^ a7) * 8)];
            bf16x8_t bk1 = *(const bf16x8_t*)&Ks[brow * 64 + (((4 + quad) ^ a7) * 8)];
            s[nt] = __builtin_amdgcn_mfma_f32_16x16x32_bf16(aq0, bk0, f32x4_t{0.f,0.f,0.f,0.f}, 0, 0, 0);
            s[nt] = __builtin_amdgcn_mfma_f32_16x16x32_bf16(aq1, bk1, s[nt], 0, 0, 0);
        }

#pragma unroll
        for (int nt = 0; nt < 4; ++nt) {
            int pcb = nt * 2 + (l16 >> 3);
#pragma unroll
            for (int r = 0; r < 4; ++r) {
                float p = exp2f(s[nt][r]);
                int pr = wrow + quad * 4 + r;
                Ps[pr * 64 + ((pcb ^ (pr & 7)) * 8) + (l16 & 7)] = f2bf(p);
            }
        }

        int arow = wrow + l16;
        bf16x8_t ap0 = *(const bf16x8_t*)&Ps[arow * 64 + ((quad ^ a7) * 8)];
        bf16x8_t ap1 = *(const bf16x8_t*)&Ps[arow * 64 + (((4 + quad) ^ a7) * 8)];
#pragma unroll
        for (int nt = 0; nt < 4; ++nt) {
            int vrow = nt * 16 + l16;
            bf16x8_t bv0 = *(const bf16x8_t*)&Vs[vrow * 64 + ((quad ^ a7) * 8)];
            bf16x8_t bv1 = *(const bf16x8_t*)&Vs[vrow * 64 + (((4 + quad) ^ a7) * 8)];
            o[nt] = __builtin_amdgcn_mfma_f32_16x16x32_bf16(ap0, bv0, o[nt], 0, 0, 0);
            o[nt] = __builtin_amdgcn_mfma_f32_16x16x32_bf16(ap1, bv1, o[nt], 0, 0, 0);
        }
        lsum = __builtin_amdgcn_mfma_f32_16x16x32_bf16(ap0, ones, lsum, 0, 0, 0);
        lsum = __builtin_amdgcn_mfma_f32_16x16x32_bf16(ap1, ones, lsum, 0, 0, 0);
    }

    int b = bh >> 4, h = bh & 15;
    float invl[4];
#pragma unroll
    for (int r = 0; r < 4; ++r) invl[r] = 1.f / lsum[r];
#pragma unroll
    for (int nt = 0; nt < 4; ++nt)
#pragma unroll
        for (int r = 0; r < 4; ++r) {
            int srow2 = q0 + wrow + quad * 4 + r;
            Og[(size_t)(b * 1024 + srow2) * 1024 + (h << 6) + nt * 16 + l16] = f2bf(o[nt][r] * invl[r]);
        }
}

// ---------------- LayerNorm over (sum of NP partials + bias) + residual ----------------
// MODE 0: resid fp32, write bf16 only      (LN1: x1b = x + LN(att))
// MODE 1: resid bf16, write fp32 only      (LN2: out = x1 + LN(pos))
// Partials are at p + z*4194304 floats (16MB stride), z in [0,NP).
template<int MODE, int NP>
__global__ __launch_bounds__(256)
void k_ln2(const float* __restrict__ p, const float* __restrict__ bias,
           const float* __restrict__ residf, const u16* __restrict__ residb,
           const float* __restrict__ g, const float* __restrict__ be,
           float* __restrict__ out, u16* __restrict__ outb)
{
    int row = blockIdx.x, tid = threadIdx.x;
    size_t base = (size_t)row * 1024;
    float xv[4]; float s = 0.f, sq = 0.f;
#pragma unroll
    for (int i = 0; i < 4; i++) {
        int c = tid + i * 256;
        float t = bias[c];
#pragma unroll
        for (int z = 0; z < NP; ++z) t += p[(size_t)z * 4194304 + base + c];
        xv[i] = t;
        s += t; sq += t * t;
    }
#pragma unroll
    for (int off = 32; off; off >>= 1) { s += __shfl_down(s, off); sq += __shfl_down(sq, off); }
    __shared__ float ss[4], ssq[4];
    int wv = tid >> 6;
    if ((tid & 63) == 0) { ss[wv] = s; ssq[wv] = sq; }
    __syncthreads();
    s  = ss[0] + ss[1] + ss[2] + ss[3];
    sq = ssq[0] + ssq[1] + ssq[2] + ssq[3];
    float mean = s * (1.f / 1024.f);
    float var  = sq * (1.f / 1024.f) - mean * mean;
    float rstd = rsqrtf(var + 1e-5f);
#pragma unroll
    for (int i = 0; i < 4; i++) {
        int c = tid + i * 256;
        float rv;
        if (MODE == 0) rv = residf[base + c];
        else {
            union { u16 u[2]; unsigned int w; float f; } cv;
            cv.w = (unsigned int)residb[base + c] << 16;
            rv = cv.f;
        }
        float y = rv + (xv[i] - mean) * rstd * g[c] + be[c];
        if (MODE == 0) outb[base + c] = f2bf(y);
        else           out[base + c] = y;
    }
}

extern "C" void kernel_launch(void* const* d_in, const int* in_sizes, int n_in,
                              void* d_out, int out_size, void* d_ws, size_t ws_size,
                              hipStream_t stream) {
    const float* x   = (const float*)d_in[0];
    const float* Wq  = (const float*)d_in[1];
    const float* bq  = (const float*)d_in[2];
    const float* Wk  = (const float*)d_in[3];
    const float* bk  = (const float*)d_in[4];
    const float* Wv  = (const float*)d_in[5];
    const float* bv  = (const float*)d_in[6];
    const float* Wo  = (const float*)d_in[7];
    const float* bo  = (const float*)d_in[8];
    const float* W1  = (const float*)d_in[9];
    const float* b1  = (const float*)d_in[10];
    const float* W2  = (const float*)d_in[11];
    const float* b2  = (const float*)d_in[12];
    const float* g1  = (const float*)d_in[13];
    const float* be1 = (const float*)d_in[14];
    const float* g2  = (const float*)d_in[15];
    const float* be2 = (const float*)d_in[16];
    float* out = (float*)d_out;

    char* w = (char*)d_ws;
    u16*   Xb    = (u16*)(w);                    //  8 MB; reused as VT after QKV
    u16*   VTb   = (u16*)(w);                    //  aliases Xb (dead after QKV)
    u16*   Wqkvt = (u16*)(w + 8388608);          //  6 MB [3072,1024] B^T
    u16*   Wot   = (u16*)(w + 14680064);         //  2 MB
    u16*   W1t   = (u16*)(w + 16777216);         //  8 MB
    u16*   W2t   = (u16*)(w + 25165824);         //  8 MB
    u16*   Qb    = (u16*)(w + 33554432);         //  8 MB [BH,S,DK]
    u16*   Kb    = (u16*)(w + 41943040);         //  8 MB
    u16*   Vb    = (u16*)(w + 50331648);         //  8 MB
    u16*   Oc    = (u16*)(w + 58720256);         //  8 MB [4096,1024]
    float* part2 = (float*)(w + 67108864);       // 32 MB split-K=2 partials (O-proj)
    // FFN2 split-K=4 partials: 64 MB over the dead Qb/Kb/Vb/Oc region
    float* part4 = (float*)(w + 33554432);
    u16*   x1b   = (u16*)(w + 117440512);        //  8 MB
    u16*   hb    = (u16*)(w + 125829120);        // 32 MB [4096,4096]

    k_cast_bf16v<<<4096, 256, 0, stream>>>(x, Xb, 1048576);
    k_qkvw_t<<<dim3(16, 16, 3), 256, 0, stream>>>(Wq, Wk, Wv, Wqkvt);
    k_transpose3<<<2304, 256, 0, stream>>>(Wo, W1, W2, Wot, W1t, W2t);

    // fused QKV projection (256x256 8-phase)
    k_gemm8<2><<<dim3(12, 16), 512, 0, stream>>>(Xb, Wqkvt, bq, bk, bv, Qb, 4096, 3072, 1024, 1024);

    // V -> VT (overwrites Xb; Xb dead after QKV)
    k_vt<<<dim3(16, 64), 256, 0, stream>>>(Vb, VTb);

    // flash attention v3
    k_attn<<<dim3(8, 64), 512, 0, stream>>>(Qb, Kb, VTb, Oc);

    // output projection, split-K=2 (128x128 kernel; N too narrow for 256 tiles)
    k_gemm_bt<0><<<dim3(8, 32, 2), 256, 0, stream>>>(Oc, Wot, nullptr, part2, 4096, 1024, 1024, 512);

    // x1b = bf16(x + LN(part0+part1+bo))
    k_ln2<0, 2><<<4096, 256, 0, stream>>>(part2, bo, x, nullptr, g1, be1, nullptr, x1b);

    // FFN1 (256x256 8-phase): hb = relu(x1b @ W1 + b1)
    k_gemm8<1><<<dim3(16, 16), 512, 0, stream>>>(x1b, W1t, b1, nullptr, nullptr, hb, 4096, 4096, 1024, 1024);

    // FFN2 (256x256 8-phase), split-K=4
    k_gemm8<0><<<dim3(4, 16, 4), 512, 0, stream>>>(hb, W2t, nullptr, nullptr, nullptr, part4, 4096, 1024, 4096, 1024);

    // out = x1b + LN(part0..3 + b2)
    k_ln2<1, 4><<<4096, 256, 0, stream>>>(part4, b2, nullptr, x1b, g2, be2, out, nullptr);
}

// Round 3
// 308.407 us; speedup vs baseline: 1.0582x; 1.0582x over previous
//
#include <hip/hip_runtime.h>
#include <hip/hip_bf16.h>
#include <hip/hip_fp16.h>

typedef unsigned short u16;
typedef short bf16x8_t __attribute__((ext_vector_type(8)));
typedef float f32x4_t  __attribute__((ext_vector_type(4)));

__device__ __forceinline__ u16 f2bf(float f) {
    __hip_bfloat16 h = __float2bfloat16(f);
    union { __hip_bfloat16 b; u16 u; } cv; cv.b = h; return cv.u;
}

// async global->LDS, 16B per lane; lds dest = wave-uniform base + lane*16
__device__ __forceinline__ void g2l16(const void* g, void* l) {
    __builtin_amdgcn_global_load_lds(
        (const __attribute__((address_space(1))) unsigned int*)g,
        (__attribute__((address_space(3))) unsigned int*)l, 16, 0, 0);
}

// ---------------- merged preprocessing: cast + Wqkv transpose + Wo/W1/W2 transpose ----------------
// blocks 0..4095: x fp32 -> Xb bf16 (float4/thread)
// blocks 4096..4863: Wq/Wk/Wv [H,1024,64] -> Wqkvt [3072][1024]
// blocks 4864..7167: Wo/W1/W2 -> Wot/W1t/W2t (64x64 tile transpose + cast)
__global__ __launch_bounds__(256)
void k_prep(const float* __restrict__ x, u16* __restrict__ Xb,
            const float* __restrict__ Wq, const float* __restrict__ Wk,
            const float* __restrict__ Wv, u16* __restrict__ Wqkvt,
            const float* __restrict__ Wo, const float* __restrict__ W1,
            const float* __restrict__ W2, u16* __restrict__ Wot,
            u16* __restrict__ W1t, u16* __restrict__ W2t)
{
    int id = blockIdx.x;
    if (id < 4096) {                                   // cast branch (whole block)
        int i = id * 256 + threadIdx.x;
        float4 f = ((const float4*)x)[i];
        ushort4 o;
        o.x = f2bf(f.x); o.y = f2bf(f.y); o.z = f2bf(f.z); o.w = f2bf(f.w);
        ((ushort4*)Xb)[i] = o;
        return;
    }
    id -= 4096;
    const float* in; u16* out; int R, C, r0, c0;       // in [R][C] -> out [C][R]
    if (id < 768) {                                    // qkvw: id = tx + 16*head + 256*proj
        int zx = id >> 8, hy = (id >> 4) & 15, tx = id & 15;
        in  = (zx == 0 ? Wq : (zx == 1 ? Wk : Wv)) + (size_t)hy * 65536;
        out = Wqkvt + ((size_t)zx * 1024 + hy * 64) * 1024;
        R = 1024; C = 64; r0 = tx * 64; c0 = 0;
    } else {
        id -= 768;
        int tx, ty;
        if (id < 256)       { in = Wo; out = Wot; R = 1024; C = 1024; tx = id & 15; ty = id >> 4; }
        else if (id < 1280) { id -= 256; in = W1; out = W1t; R = 1024; C = 4096; tx = id & 63; ty = id >> 6; }
        else                { id -= 1280; in = W2; out = W2t; R = 4096; C = 1024; tx = id & 15; ty = id >> 4; }
        r0 = ty * 64; c0 = tx * 64;
    }
    __shared__ float t[64][65];
    int lc = threadIdx.x & 63, lr = threadIdx.x >> 6;
#pragma unroll
    for (int p = 0; p < 16; ++p) {
        int rr = p * 4 + lr;
        t[rr][lc] = in[(size_t)(r0 + rr) * C + c0 + lc];
    }
    __syncthreads();
#pragma unroll
    for (int p = 0; p < 16; ++p) {
        int cc = p * 4 + lr;
        out[(size_t)(c0 + cc) * R + r0 + lc] = f2bf(t[lc][cc]);
    }
}

// ---------------- V [bh][s][dk] -> VT [bh][dk][s] bf16 (padded-LDS transpose) ----------------
__global__ __launch_bounds__(256)
void k_vt(const u16* __restrict__ V, u16* __restrict__ VT) {
    __shared__ u16 t[64 * 72];
    int bh = blockIdx.y, s0 = blockIdx.x * 64;
    const u16* Vp = V + (size_t)bh * 65536;
    u16* Tp = VT + (size_t)bh * 65536;
    int tid = threadIdx.x;
    int r = tid >> 3, c = (tid & 7) * 8;
    *(uint4*)&t[r * 72 + c]        = *(const uint4*)&Vp[(size_t)(s0 + r) * 64 + c];
    *(uint4*)&t[(r + 32) * 72 + c] = *(const uint4*)&Vp[(size_t)(s0 + r + 32) * 64 + c];
    __syncthreads();
    int d = tid >> 2, sl0 = (tid & 3) * 16;
    uint4 outv[2];
    u16* ov = (u16*)outv;
#pragma unroll
    for (int j = 0; j < 16; ++j) ov[j] = t[(sl0 + j) * 72 + d];
    *(uint4*)&Tp[(size_t)d * 1024 + s0 + sl0]     = outv[0];
    *(uint4*)&Tp[(size_t)d * 1024 + s0 + sl0 + 8] = outv[1];
}

// ---------------- 128x128 bf16 GEMM, B pre-transposed, BK=64, split-K -> fp16 partials ----------------
// XCD-aware bijective swizzle on (bx,by) within each z-slice (nwg % 8 == 0 for all uses).
// Partial store: __half at out + z*M*N (halves the split-K round-trip traffic vs fp32).
__global__ __launch_bounds__(256, 4)
void k_gemm_bt(const u16* __restrict__ A, const u16* __restrict__ Bt,
               void* __restrict__ out, int M, int N, int K, int kchunk)
{
    __shared__ __align__(16) u16 As[2 * 128 * 32];
    __shared__ __align__(16) u16 Bs[2 * 128 * 32];
    int tid = threadIdx.x;
    int wave = tid >> 6, lane = tid & 63;

    int nx = gridDim.x, nwg = nx * gridDim.y;
    int f  = blockIdx.x + nx * blockIdx.y;
    int f2 = (f & 7) * (nwg >> 3) + (f >> 3);
    int bx = f2 % nx, by = f2 / nx;
    int row0 = by * 128, col0 = bx * 128;

    int z = blockIdx.z;
    int kbeg = z * kchunk;

    int lrow = lane >> 2, lcol = (lane & 3) * 8;
    const u16* pA0 = A  + (size_t)(row0 + wave * 16 + lrow) * K + kbeg + lcol;
    const u16* pA1 = pA0 + (size_t)64 * K;
    const u16* pB0 = Bt + (size_t)(col0 + wave * 16 + lrow) * K + kbeg + lcol;
    const u16* pB1 = pB0 + (size_t)64 * K;
    u16* lA0 = &As[wave * 512];
    u16* lA1 = &As[2048 + wave * 512];
    u16* lB0 = &Bs[wave * 512];
    u16* lB1 = &Bs[2048 + wave * 512];

    int wm = (wave >> 1) * 64, wn = (wave & 1) * 64;
    int quad = lane >> 4, l16 = lane & 15;

    f32x4_t acc[4][4];
#pragma unroll
    for (int i = 0; i < 4; i++)
#pragma unroll
        for (int j = 0; j < 4; j++) acc[i][j] = f32x4_t{0.f, 0.f, 0.f, 0.f};

    for (int kk = 0; kk < kchunk; kk += 64) {
        __syncthreads();
        g2l16(pA0, lA0);      g2l16(pA1, lA1);
        g2l16(pA0 + 32, lA0 + 4096); g2l16(pA1 + 32, lA1 + 4096);
        g2l16(pB0, lB0);      g2l16(pB1, lB1);
        g2l16(pB0 + 32, lB0 + 4096); g2l16(pB1 + 32, lB1 + 4096);
        pA0 += 64; pA1 += 64; pB0 += 64; pB1 += 64;
        __syncthreads();

#pragma unroll
        for (int s = 0; s < 2; ++s) {
            const u16* as = &As[s * 4096];
            const u16* bs = &Bs[s * 4096];
            bf16x8_t a[4], b[4];
#pragma unroll
            for (int i = 0; i < 4; ++i)
                a[i] = *(const bf16x8_t*)&as[(wm + i * 16 + l16) * 32 + quad * 8];
#pragma unroll
            for (int j = 0; j < 4; ++j)
                b[j] = *(const bf16x8_t*)&bs[(wn + j * 16 + l16) * 32 + quad * 8];
#pragma unroll
            for (int i = 0; i < 4; ++i)
#pragma unroll
                for (int j = 0; j < 4; ++j)
                    acc[i][j] = __builtin_amdgcn_mfma_f32_16x16x32_bf16(a[i], b[j], acc[i][j], 0, 0, 0);
        }
    }

#pragma unroll
    for (int i = 0; i < 4; ++i)
#pragma unroll
        for (int j = 0; j < 4; ++j)
#pragma unroll
            for (int r = 0; r < 4; ++r) {
                int row = row0 + wm + i * 16 + quad * 4 + r;
                int col = col0 + wn + j * 16 + l16;
                ((__half*)out)[(size_t)z * M * N + (size_t)row * N + col] =
                    __float2half(acc[i][j][r]);
            }
}

// ---------------- 256x128 bf16 GEMM, B pre-transposed, BK=64, 512 threads ----------------
// 8 waves = 4 row x 2 col of 64x64. 2-3 blocks/CU (48 KiB LDS) -> implicit wave overlap.
// EPI 1: relu(acc+bias0) -> bf16 [M,N]
// EPI 2: fused-QKV store: Q,K,V -> [bh][s][k] (Q scaled 0.125*log2e), coalesced
template<int EPI>
__global__ __launch_bounds__(512, 4)
void k_gemm_bt2(const u16* __restrict__ A, const u16* __restrict__ Bt,
                const float* __restrict__ bias0, const float* __restrict__ bias1,
                const float* __restrict__ bias2, void* __restrict__ out,
                int M, int N, int K)
{
    __shared__ __align__(16) u16 As[2 * 256 * 32];   // 2 subtiles of [256][32]
    __shared__ __align__(16) u16 Bs[2 * 128 * 32];   // 2 subtiles of [128][32]
    int tid = threadIdx.x;
    int wave = tid >> 6, lane = tid & 63;
    int row0 = blockIdx.y * 256, col0 = blockIdx.x * 128;

    int lrow = lane >> 2, lcol = (lane & 3) * 8;
    const u16* pA0 = A  + (size_t)(row0 + wave * 16 + lrow) * K + lcol;         // rows 0..127
    const u16* pA1 = pA0 + (size_t)128 * K;                                     // rows 128..255
    const u16* pB0 = Bt + (size_t)(col0 + wave * 16 + lrow) * K + lcol;         // rows 0..127
    u16* lA0 = &As[wave * 512];
    u16* lA1 = &As[4096 + wave * 512];
    u16* lB0 = &Bs[wave * 512];

    int wm = (wave >> 1) * 64, wn = (wave & 1) * 64;
    int quad = lane >> 4, l16 = lane & 15;

    f32x4_t acc[4][4];
#pragma unroll
    for (int i = 0; i < 4; i++)
#pragma unroll
        for (int j = 0; j < 4; j++) acc[i][j] = f32x4_t{0.f, 0.f, 0.f, 0.f};

    for (int kk = 0; kk < K; kk += 64) {
        __syncthreads();
        g2l16(pA0, lA0);           g2l16(pA1, lA1);
        g2l16(pA0 + 32, lA0 + 8192); g2l16(pA1 + 32, lA1 + 8192);
        g2l16(pB0, lB0);           g2l16(pB0 + 32, lB0 + 4096);
        pA0 += 64; pA1 += 64; pB0 += 64;
        __syncthreads();

#pragma unroll
        for (int s = 0; s < 2; ++s) {
            const u16* as = &As[s * 8192];
            const u16* bs = &Bs[s * 4096];
            bf16x8_t a[4], b[4];
#pragma unroll
            for (int i = 0; i < 4; ++i)
                a[i] = *(const bf16x8_t*)&as[(wm + i * 16 + l16) * 32 + quad * 8];
#pragma unroll
            for (int j = 0; j < 4; ++j)
                b[j] = *(const bf16x8_t*)&bs[(wn + j * 16 + l16) * 32 + quad * 8];
#pragma unroll
            for (int i = 0; i < 4; ++i)
#pragma unroll
                for (int j = 0; j < 4; ++j)
                    acc[i][j] = __builtin_amdgcn_mfma_f32_16x16x32_bf16(a[i], b[j], acc[i][j], 0, 0, 0);
        }
    }

#pragma unroll
    for (int i = 0; i < 4; ++i)
#pragma unroll
        for (int j = 0; j < 4; ++j)
#pragma unroll
            for (int r = 0; r < 4; ++r) {
                int row = row0 + wm + i * 16 + quad * 4 + r;
                int col = col0 + wn + j * 16 + l16;
                float v = acc[i][j][r];
                if (EPI == 1) {
                    ((u16*)out)[(size_t)row * N + col] = f2bf(fmaxf(v + bias0[col], 0.f));
                } else {
                    int proj = col >> 10, within = col & 1023;
                    const float* bp = proj == 0 ? bias0 : (proj == 1 ? bias1 : bias2);
                    v += bp[within];
                    if (proj == 0) v *= 0.18033688f;   // 0.125 * log2(e)
                    int h = within >> 6, kq = within & 63;
                    int b_ = row >> 10, s_ = row & 1023;
                    size_t bh = (size_t)((b_ << 4) + h);
                    ((u16*)out)[(size_t)proj * 4194304 + bh * 65536 + (s_ << 6) + kq] = f2bf(v);
                }
            }
}

// ---------------- flash attention v3 (no-max softmax, MFMA row-sum) ----------------
// XCD swizzle: all 8 q-blocks of one bh land on the same XCD -> K/V (256KB/bh) L2-resident.
__global__ __launch_bounds__(512, 4)
void k_attn(const u16* __restrict__ Qg, const u16* __restrict__ Kg,
            const u16* __restrict__ VTg, u16* __restrict__ Og)
{
    __shared__ __align__(16) u16 Ks[64 * 64];
    __shared__ __align__(16) u16 Vs[64 * 64];
    __shared__ __align__(16) u16 Ps[128 * 64];

    int tid = threadIdx.x, wave = tid >> 6, lane = tid & 63;
    int quad = lane >> 4, l16 = lane & 15;

    int f  = blockIdx.x + gridDim.x * blockIdx.y;
    int f2 = (f & 7) * ((gridDim.x * gridDim.y) >> 3) + (f >> 3);
    int bh = f2 >> 3;
    int q0 = (f2 & 7) * 128;
    int wrow = wave * 16;

    const u16* Qp  = Qg  + (size_t)bh * 65536;
    const u16* Kp  = Kg  + (size_t)bh * 65536;
    const u16* VTp = VTg + (size_t)bh * 65536;

    int arow_g = q0 + wrow + l16;
    bf16x8_t aq0 = *(const bf16x8_t*)&Qp[(size_t)arow_g * 64 + quad * 8];
    bf16x8_t aq1 = *(const bf16x8_t*)&Qp[(size_t)arow_g * 64 + 32 + quad * 8];

    int srow = tid >> 3, scb = tid & 7;
    uint4 kreg = *(const uint4*)&Kp[(size_t)srow * 64 + scb * 8];
    uint4 vreg = *(const uint4*)&VTp[(size_t)srow * 1024 + scb * 8];
    u16* kdst = &Ks[srow * 64 + ((scb ^ (srow & 7)) * 8)];
    u16* vdst = &Vs[srow * 64 + ((scb ^ (srow & 7)) * 8)];

    f32x4_t o[4], lsum;
#pragma unroll
    for (int nt = 0; nt < 4; ++nt) o[nt] = f32x4_t{0.f, 0.f, 0.f, 0.f};
    lsum = f32x4_t{0.f, 0.f, 0.f, 0.f};

    bf16x8_t ones;
#pragma unroll
    for (int j = 0; j < 8; ++j) ones[j] = (short)0x3F80;

    int a7 = l16 & 7;

    for (int kv0 = 0; kv0 < 1024; kv0 += 64) {
        __syncthreads();
        *(uint4*)kdst = kreg;
        *(uint4*)vdst = vreg;
        __syncthreads();
        if (kv0 < 960) {
            kreg = *(const uint4*)&Kp[(size_t)(kv0 + 64 + srow) * 64 + scb * 8];
            vreg = *(const uint4*)&VTp[(size_t)srow * 1024 + kv0 + 64 + scb * 8];
        }

        f32x4_t s[4];
#pragma unroll
        for (int nt = 0; nt < 4; ++nt) {
            int brow = nt * 16 + l16;
            bf16x8_t bk0 = *(const bf16x8_t*)&Ks[brow * 64 + ((quad ^ a7) * 8)];
            bf16x8_t bk1 = *(const bf16x8_t*)&Ks[brow * 64 + (((4 + quad) ^ a7) * 8)];
            s[nt] = __builtin_amdgcn_mfma_f32_16x16x32_bf16(aq0, bk0, f32x4_t{0.f,0.f,0.f,0.f}, 0, 0, 0);
            s[nt] = __builtin_amdgcn_mfma_f32_16x16x32_bf16(aq1, bk1, s[nt], 0, 0, 0);
        }

#pragma unroll
        for (int nt = 0; nt < 4; ++nt) {
            int pcb = nt * 2 + (l16 >> 3);
#pragma unroll
            for (int r = 0; r < 4; ++r) {
                float p = exp2f(s[nt][r]);
                int pr = wrow + quad * 4 + r;
                Ps[pr * 64 + ((pcb ^ (pr & 7)) * 8) + (l16 & 7)] = f2bf(p);
            }
        }

        int arow = wrow + l16;
        bf16x8_t ap0 = *(const bf16x8_t*)&Ps[arow * 64 + ((quad ^ a7) * 8)];
        bf16x8_t ap1 = *(const bf16x8_t*)&Ps[arow * 64 + (((4 + quad) ^ a7) * 8)];
#pragma unroll
        for (int nt = 0; nt < 4; ++nt) {
            int vrow = nt * 16 + l16;
            bf16x8_t bv0 = *(const bf16x8_t*)&Vs[vrow * 64 + ((quad ^ a7) * 8)];
            bf16x8_t bv1 = *(const bf16x8_t*)&Vs[vrow * 64 + (((4 + quad) ^ a7) * 8)];
            o[nt] = __builtin_amdgcn_mfma_f32_16x16x32_bf16(ap0, bv0, o[nt], 0, 0, 0);
            o[nt] = __builtin_amdgcn_mfma_f32_16x16x32_bf16(ap1, bv1, o[nt], 0, 0, 0);
        }
        lsum = __builtin_amdgcn_mfma_f32_16x16x32_bf16(ap0, ones, lsum, 0, 0, 0);
        lsum = __builtin_amdgcn_mfma_f32_16x16x32_bf16(ap1, ones, lsum, 0, 0, 0);
    }

    int b = bh >> 4, h = bh & 15;
    float invl[4];
#pragma unroll
    for (int r = 0; r < 4; ++r) invl[r] = 1.f / lsum[r];
#pragma unroll
    for (int nt = 0; nt < 4; ++nt)
#pragma unroll
        for (int r = 0; r < 4; ++r) {
            int srow2 = q0 + wrow + quad * 4 + r;
            Og[(size_t)(b * 1024 + srow2) * 1024 + (h << 6) + nt * 16 + l16] = f2bf(o[nt][r] * invl[r]);
        }
}

// ---------------- LayerNorm over (sum of NP fp16 partials + bias) + residual ----------------
// MODE 0: resid fp32, write bf16 only      (LN1: x1b = x + LN(att))
// MODE 1: resid bf16, write fp32 only      (LN2: out = x1 + LN(pos))
// Partials: __half at p + z*4194304 elements (8MB stride), z in [0,NP).
template<int MODE, int NP>
__global__ __launch_bounds__(256)
void k_ln2(const __half* __restrict__ p, const float* __restrict__ bias,
           const float* __restrict__ residf, const u16* __restrict__ residb,
           const float* __restrict__ g, const float* __restrict__ be,
           float* __restrict__ out, u16* __restrict__ outb)
{
    int row = blockIdx.x, tid = threadIdx.x;
    size_t base = (size_t)row * 1024;
    float xv[4]; float s = 0.f, sq = 0.f;
#pragma unroll
    for (int i = 0; i < 4; i++) {
        int c = tid + i * 256;
        float t = bias[c];
#pragma unroll
        for (int z = 0; z < NP; ++z) t += __half2float(p[(size_t)z * 4194304 + base + c]);
        xv[i] = t;
        s += t; sq += t * t;
    }
#pragma unroll
    for (int off = 32; off; off >>= 1) { s += __shfl_down(s, off); sq += __shfl_down(sq, off); }
    __shared__ float ss[4], ssq[4];
    int wv = tid >> 6;
    if ((tid & 63) == 0) { ss[wv] = s; ssq[wv] = sq; }
    __syncthreads();
    s  = ss[0] + ss[1] + ss[2] + ss[3];
    sq = ssq[0] + ssq[1] + ssq[2] + ssq[3];
    float mean = s * (1.f / 1024.f);
    float var  = sq * (1.f / 1024.f) - mean * mean;
    float rstd = rsqrtf(var + 1e-5f);
#pragma unroll
    for (int i = 0; i < 4; i++) {
        int c = tid + i * 256;
        float rv;
        if (MODE == 0) rv = residf[base + c];
        else {
            union { u16 u[2]; unsigned int w; float f; } cv;
            cv.w = (unsigned int)residb[base + c] << 16;
            rv = cv.f;
        }
        float y = rv + (xv[i] - mean) * rstd * g[c] + be[c];
        if (MODE == 0) outb[base + c] = f2bf(y);
        else           out[base + c] = y;
    }
}

extern "C" void kernel_launch(void* const* d_in, const int* in_sizes, int n_in,
                              void* d_out, int out_size, void* d_ws, size_t ws_size,
                              hipStream_t stream) {
    const float* x   = (const float*)d_in[0];
    const float* Wq  = (const float*)d_in[1];
    const float* bq  = (const float*)d_in[2];
    const float* Wk  = (const float*)d_in[3];
    const float* bk  = (const float*)d_in[4];
    const float* Wv  = (const float*)d_in[5];
    const float* bv  = (const float*)d_in[6];
    const float* Wo  = (const float*)d_in[7];
    const float* bo  = (const float*)d_in[8];
    const float* W1  = (const float*)d_in[9];
    const float* b1  = (const float*)d_in[10];
    const float* W2  = (const float*)d_in[11];
    const float* b2  = (const float*)d_in[12];
    const float* g1  = (const float*)d_in[13];
    const float* be1 = (const float*)d_in[14];
    const float* g2  = (const float*)d_in[15];
    const float* be2 = (const float*)d_in[16];
    float* out = (float*)d_out;

    char* w = (char*)d_ws;
    u16*    Xb    = (u16*)(w);                    //  8 MB; reused as VT after QKV
    u16*    VTb   = (u16*)(w);                    //  aliases Xb (dead after QKV)
    u16*    Wqkvt = (u16*)(w + 8388608);          //  6 MB [3072,1024] B^T
    u16*    Wot   = (u16*)(w + 14680064);         //  2 MB
    u16*    W1t   = (u16*)(w + 16777216);         //  8 MB
    u16*    W2t   = (u16*)(w + 25165824);         //  8 MB
    u16*    Qb    = (u16*)(w + 33554432);         //  8 MB [BH,S,DK]
    u16*    Kb    = (u16*)(w + 41943040);         //  8 MB
    u16*    Vb    = (u16*)(w + 50331648);         //  8 MB
    u16*    Oc    = (u16*)(w + 58720256);         //  8 MB [4096,1024]
    // FFN2 split-K=4 fp16 partials: 32 MB over the dead Qb/Kb/Vb/Oc region
    __half* part4 = (__half*)(w + 33554432);
    __half* part2 = (__half*)(w + 67108864);      // 16 MB split-K=2 fp16 partials (O-proj)
    u16*    x1b   = (u16*)(w + 117440512);        //  8 MB
    u16*    hb    = (u16*)(w + 125829120);        // 32 MB [4096,4096]

    // merged cast + all weight transposes (one launch)
    k_prep<<<7168, 256, 0, stream>>>(x, Xb, Wq, Wk, Wv, Wqkvt, Wo, W1, W2, Wot, W1t, W2t);

    // fused QKV projection (256x128 tile, 2-phase)
    k_gemm_bt2<2><<<dim3(24, 16), 512, 0, stream>>>(Xb, Wqkvt, bq, bk, bv, Qb, 4096, 3072, 1024);

    // V -> VT (overwrites Xb; Xb dead after QKV)
    k_vt<<<dim3(16, 64), 256, 0, stream>>>(Vb, VTb);

    // flash attention v3
    k_attn<<<dim3(8, 64), 512, 0, stream>>>(Qb, Kb, VTb, Oc);

    // output projection, split-K=2, fp16 partials
    k_gemm_bt<<<dim3(8, 32, 2), 256, 0, stream>>>(Oc, Wot, part2, 4096, 1024, 1024, 512);

    // x1b = bf16(x + LN(part0+part1+bo))
    k_ln2<0, 2><<<4096, 256, 0, stream>>>(part2, bo, x, nullptr, g1, be1, nullptr, x1b);

    // FFN1 (256x128 tile, 2-phase): hb = relu(x1b @ W1 + b1)
    k_gemm_bt2<1><<<dim3(32, 16), 512, 0, stream>>>(x1b, W1t, b1, nullptr, nullptr, hb, 4096, 4096, 1024);

    // FFN2, split-K=4, fp16 partials (Qb/Kb/Vb/Oc dead by now)
    k_gemm_bt<<<dim3(8, 32, 4), 256, 0, stream>>>(hb, W2t, part4, 4096, 1024, 4096, 1024);

    // out = x1b + LN(part0..3 + b2)
    k_ln2<1, 4><<<4096, 256, 0, stream>>>(part4, b2, nullptr, x1b, g2, be2, out, nullptr);
}